// Round 3
// baseline (5347.929 us; speedup 1.0000x reference)
//
#include <hip/hip_runtime.h>
#include <hip/hip_bf16.h>
#include <math.h>

// ---- problem constants ----
#define NH   12
#define DM   768
#define HD   64
#define SEQ  512
#define NB   2
#define MR   (NB*SEQ)     // 1024 rows of residual stream
#define C3   (3*DM)       // 2304
#define DFF  (4*DM)       // 3072
#define NV   50257
#define NL   12

typedef __bf16  bf16x8 __attribute__((ext_vector_type(8)));
typedef float   floatx4 __attribute__((ext_vector_type(4)));
typedef __hip_bfloat16 bf16;

// dual-dtype input load: inputs are either fp32 or bf16, decided at runtime
__device__ __forceinline__ float ldIn(const void* p, size_t i, int fp32) {
    return fp32 ? ((const float*)p)[i]
                : __bfloat162float(((const bf16*)p)[i]);
}

// detect input dtype from ln1_w[0] == 1.0 exactly:
// fp32 LE bytes 00 00 80 3F -> halfword0 == 0x0000 ; bf16 1.0 == 0x3F80
__global__ void k_detect(const unsigned short* __restrict__ w, int* __restrict__ flag) {
    *flag = (w[0] == 0) ? 1 : 0;
}

// ---------------- embed: x = tok[ids] + pos (fp32 out) ----------------
__global__ __launch_bounds__(256) void k_embed(const int* __restrict__ ids,
                                               const void* __restrict__ tok,
                                               const void* __restrict__ pos,
                                               float* __restrict__ x,
                                               const int* __restrict__ flagp) {
    int fp32 = *flagp;
    int idx = blockIdx.x * 256 + threadIdx.x;          // over MR*DM
    int row = idx / DM;
    int d   = idx - row * DM;
    int t   = row & (SEQ - 1);
    int id  = ids[row];
    x[idx] = ldIn(tok, (size_t)id * DM + d, fp32) + ldIn(pos, (size_t)t * DM + d, fp32);
}

// ---------------- LayerNorm (wave per row): fp32 in -> bf16 out ----------------
// w/b are external inputs at element offset `woff`
__global__ __launch_bounds__(64) void k_ln(const float* __restrict__ x,
                                           const void* __restrict__ w,
                                           const void* __restrict__ b,
                                           size_t woff,
                                           bf16* __restrict__ out,
                                           const int* __restrict__ flagp) {
    int fp32 = *flagp;
    int row = blockIdx.x;
    int lane = threadIdx.x;
    const float* xr = x + (size_t)row * DM;
    float vals[12];
    float s = 0.f, s2 = 0.f;
    #pragma unroll
    for (int i = 0; i < 12; i++) {
        float v = xr[lane + i * 64];
        vals[i] = v; s += v; s2 += v * v;
    }
    #pragma unroll
    for (int off = 32; off > 0; off >>= 1) {
        s  += __shfl_xor(s, off);
        s2 += __shfl_xor(s2, off);
    }
    float mean = s * (1.f / DM);
    float var  = s2 * (1.f / DM) - mean * mean;
    float rs   = rsqrtf(var + 1e-5f);
    #pragma unroll
    for (int i = 0; i < 12; i++) {
        int d = lane + i * 64;
        float wv = ldIn(w, woff + d, fp32);
        float bv = ldIn(b, woff + d, fp32);
        out[(size_t)row * DM + d] = __float2bfloat16((vals[i] - mean) * rs * wv + bv);
    }
}

// ---------------- GEMM: C[M,N] = A[M,K](bf16) * W[N,K]^T (+bias)(+resid)(+gelu) ----------------
// A: internal bf16. W at element offset woff, bias at boff (external, dtype per flag).
// one wave per 64x64 tile, 4x4 of 16x16x32 MFMAs.
// frag layouts per m89/m91/m92: A[m=lane&15][k=quad*8+t]; B=W[n=lane&15][k=quad*8+t];
// C/D: col=lane&15, row=quad*4+reg
__global__ __launch_bounds__(64) void k_gemm(const bf16* __restrict__ A,
                                             const void* __restrict__ W, size_t woff,
                                             const void* __restrict__ bias, size_t boff,
                                             const float* __restrict__ resid,
                                             float* __restrict__ outF,
                                             bf16* __restrict__ outB,
                                             void* __restrict__ outExt,
                                             int M, int N, int K, int act,
                                             const int* __restrict__ flagp) {
    int fp32 = *flagp;
    int lane = threadIdx.x;
    int r    = lane & 15;
    int quad = lane >> 4;
    int m0 = blockIdx.y * 64;
    int n0 = blockIdx.x * 64;

    floatx4 acc[4][4];
    #pragma unroll
    for (int i = 0; i < 4; i++)
        #pragma unroll
        for (int j = 0; j < 4; j++)
            acc[i][j] = (floatx4){0.f, 0.f, 0.f, 0.f};

    int wr[4];
    #pragma unroll
    for (int j = 0; j < 4; j++) {
        int n = n0 + j * 16 + r;
        wr[j] = n < N ? n : N - 1;   // clamp loads for ragged N (lm_head)
    }

    for (int k0 = 0; k0 < K; k0 += 32) {
        bf16x8 a[4], b[4];
        #pragma unroll
        for (int i = 0; i < 4; i++)
            a[i] = *reinterpret_cast<const bf16x8*>(A + (size_t)(m0 + i * 16 + r) * K + k0 + quad * 8);
        if (fp32) {
            #pragma unroll
            for (int j = 0; j < 4; j++) {
                const float* p = (const float*)W + woff + (size_t)wr[j] * K + k0 + quad * 8;
                #pragma unroll
                for (int t = 0; t < 8; t++) b[j][t] = (__bf16)p[t];
            }
        } else {
            #pragma unroll
            for (int j = 0; j < 4; j++)
                b[j] = *reinterpret_cast<const bf16x8*>((const bf16*)W + woff + (size_t)wr[j] * K + k0 + quad * 8);
        }
        #pragma unroll
        for (int i = 0; i < 4; i++)
            #pragma unroll
            for (int j = 0; j < 4; j++)
                acc[i][j] = __builtin_amdgcn_mfma_f32_16x16x32_bf16(a[i], b[j], acc[i][j], 0, 0, 0);
    }

    #pragma unroll
    for (int j = 0; j < 4; j++) {
        int col = n0 + j * 16 + r;
        if (col >= N) continue;
        float bv = bias ? ldIn(bias, boff + col, fp32) : 0.f;
        #pragma unroll
        for (int i = 0; i < 4; i++) {
            #pragma unroll
            for (int rr = 0; rr < 4; rr++) {
                int row = m0 + i * 16 + quad * 4 + rr;
                float v = acc[i][j][rr] + bv;
                if (resid) v += resid[(size_t)row * N + col];
                if (act) v = 0.5f * v * (1.f + erff(v * 0.70710678118f));  // exact GELU
                if (outF)      outF[(size_t)row * N + col] = v;
                else if (outB) outB[(size_t)row * N + col] = __float2bfloat16(v);
                else {
                    if (fp32) ((float*)outExt)[(size_t)row * N + col] = v;
                    else      ((bf16*)outExt)[(size_t)row * N + col] = __float2bfloat16(v);
                }
            }
        }
    }
}

// ---------------- fused attention: one wave per (b,h,q), all-internal bf16 ----------------
__global__ __launch_bounds__(64) void k_attn(const bf16* __restrict__ qkv,
                                             bf16* __restrict__ o) {
    int bhq  = blockIdx.x;
    int lane = threadIdx.x;
    int q = bhq & (SEQ - 1);
    int h = (bhq >> 9) % NH;
    int b = bhq / (SEQ * NH);

    __shared__ float qs[HD];
    __shared__ float p[SEQ];

    const bf16* qrow = qkv + ((size_t)(b * SEQ + q)) * C3 + h * HD;
    qs[lane] = __bfloat162float(qrow[lane]);
    __syncthreads();

    // scores for k <= q only (no mask values materialized)
    float mx = -1e30f;
    for (int k = lane; k <= q; k += 64) {
        const bf16* krow = qkv + ((size_t)(b * SEQ + k)) * C3 + DM + h * HD;
        float acc = 0.f;
        #pragma unroll 8
        for (int d = 0; d < HD; d++) acc += qs[d] * __bfloat162float(krow[d]);
        float s = acc * 0.125f;
        p[k] = s;
        mx = fmaxf(mx, s);
    }
    #pragma unroll
    for (int off = 32; off > 0; off >>= 1) mx = fmaxf(mx, __shfl_xor(mx, off));

    float sum = 0.f;
    for (int k = lane; k <= q; k += 64) {
        float e = expf(p[k] - mx);
        p[k] = e;
        sum += e;
    }
    #pragma unroll
    for (int off = 32; off > 0; off >>= 1) sum += __shfl_xor(sum, off);
    float inv = 1.f / sum;
    __syncthreads();

    // AV: lane = d
    const bf16* vb = qkv + ((size_t)(b * SEQ)) * C3 + 2 * DM + h * HD + lane;
    float acc = 0.f;
    for (int k = 0; k <= q; k++) acc += p[k] * __bfloat162float(vb[(size_t)k * C3]);
    o[((size_t)(b * SEQ + q)) * DM + h * HD + lane] = __float2bfloat16(acc * inv);
}

extern "C" void kernel_launch(void* const* d_in, const int* in_sizes, int n_in,
                              void* d_out, int out_size, void* d_ws, size_t ws_size,
                              hipStream_t stream) {
    const int*  ids  = (const int*)d_in[0];
    const void* tok  = d_in[1];
    const void* pos  = d_in[2];
    const void* ln1w = d_in[3];
    const void* ln1b = d_in[4];
    const void* qkvw = d_in[5];
    const void* qkvb = d_in[6];
    const void* projw= d_in[7];
    const void* projb= d_in[8];
    const void* ln2w = d_in[9];
    const void* ln2b = d_in[10];
    const void* fc1w = d_in[11];
    const void* fc1b = d_in[12];
    const void* fc2w = d_in[13];
    const void* fc2b = d_in[14];
    const void* lnfw = d_in[15];
    const void* lnfb = d_in[16];

    // workspace plan (~10.5 MB total; lifetimes overlapped)
    char* w = (char*)d_ws;
    int*   flag = (int*)(w);                     // 256 B slot
    float* x    = (float*)(w + 256);             // 3,145,728 B  residual fp32 [1024,768]
    bf16*  act  = (bf16*)(w + 256 + 3145728);    // 6,291,456 B  qkv[1024,2304] / gelu[1024,3072] bf16
    bf16*  hb   = (bf16*)(w + 256 + 9437184);    // 1,572,864 B  ln-out / attn-out bf16 [1024,768]

    k_detect<<<1, 1, 0, stream>>>((const unsigned short*)ln1w, flag);
    k_embed<<<(MR * DM) / 256, 256, 0, stream>>>(ids, tok, pos, x, flag);

    for (int l = 0; l < NL; l++) {
        size_t o_ln = (size_t)l * DM;
        size_t o_qw = (size_t)l * C3 * DM,   o_qb  = (size_t)l * C3;
        size_t o_pw = (size_t)l * DM * DM,   o_pb  = (size_t)l * DM;
        size_t o_f1w= (size_t)l * DFF * DM,  o_f1b = (size_t)l * DFF;
        size_t o_f2w= (size_t)l * DM * DFF,  o_f2b = (size_t)l * DM;

        // h = LN1(x)
        k_ln<<<MR, 64, 0, stream>>>(x, ln1w, ln1b, o_ln, hb, flag);
        // qkv = h @ qkv_w^T + qkv_b -> bf16 [1024,2304]
        k_gemm<<<dim3(C3 / 64, MR / 64), 64, 0, stream>>>(hb, qkvw, o_qw, qkvb, o_qb,
            nullptr, nullptr, act, nullptr, MR, C3, DM, 0, flag);
        // fused attention -> hb
        k_attn<<<NB * NH * SEQ, 64, 0, stream>>>(act, hb);
        // x = x + o @ proj_w^T + proj_b
        k_gemm<<<dim3(DM / 64, MR / 64), 64, 0, stream>>>(hb, projw, o_pw, projb, o_pb,
            x, x, nullptr, nullptr, MR, DM, DM, 0, flag);
        // h = LN2(x)
        k_ln<<<MR, 64, 0, stream>>>(x, ln2w, ln2b, o_ln, hb, flag);
        // g = gelu(h @ fc1_w^T + fc1_b) -> bf16 [1024,3072]
        k_gemm<<<dim3(DFF / 64, MR / 64), 64, 0, stream>>>(hb, fc1w, o_f1w, fc1b, o_f1b,
            nullptr, nullptr, act, nullptr, MR, DFF, DM, 1, flag);
        // x = x + g @ fc2_w^T + fc2_b
        k_gemm<<<dim3(DM / 64, MR / 64), 64, 0, stream>>>(act, fc2w, o_f2w, fc2b, o_f2b,
            x, x, nullptr, nullptr, MR, DM, DFF, 0, flag);
    }

    // final LN + weight-tied lm_head (output dtype per flag)
    k_ln<<<MR, 64, 0, stream>>>(x, lnfw, lnfb, 0, hb, flag);
    k_gemm<<<dim3((NV + 63) / 64, MR / 64), 64, 0, stream>>>(hb, tok, 0, nullptr, 0,
        nullptr, nullptr, nullptr, d_out, MR, NV, DM, 0, flag);
}